// Round 8
// baseline (11783.228 us; speedup 1.0000x reference)
//
#include <hip/hip_runtime.h>

// Problem dims (fixed by reference): N=256, T=32, F=H=512, L=2
#define HD 512
#define TT 32
#define NB 256
#define SEQROWS 8193          // 1 zero row + up to 8192 chain steps
#define GC 64                 // chain WGs; each owns RPW rows of BOTH layers
#define RPW 8                 // rows per WG (GC*RPW = HD)
#define SENT_U 0x7FC0ABCDu    // quiet-NaN sentinel: unreachable by GRU math
#define DEADLINE_TICKS 6000000ll   // 60 ms @ 100 MHz: bounded wall-clock, never hang

__device__ __forceinline__ float fast_sigmoid(float x) { return 1.f / (1.f + __expf(-x)); }
__device__ __forceinline__ float fast_tanh(float x)    { return 1.f - 2.f / (__expf(2.f * x) + 1.f); }
__device__ __forceinline__ void pinv(float& v) { asm volatile("" : "+v"(v)); }

__device__ __forceinline__ float coh_load(const float* p) {
    return __hip_atomic_load(p, __ATOMIC_RELAXED, __HIP_MEMORY_SCOPE_AGENT);
}
__device__ __forceinline__ void coh_store(float* p, float v) {
    __hip_atomic_store(p, v, __ATOMIC_RELAXED, __HIP_MEMORY_SCOPE_AGENT);
}
__device__ __forceinline__ long long rtclock() {
    return (long long)__builtin_amdgcn_s_memrealtime();
}

// ---------------------------------------------------------------------------
// init: block 0 -> dates scan, active list, jmap, S, zero h row 0, out dates;
//       blocks 1..1024 -> sentinel-fill rows 1..8192 of both fp32 h buffers.
// (verbatim R5 structure — proven)
// ---------------------------------------------------------------------------
__global__ __launch_bounds__(256) void init_kernel(
    const int* __restrict__ dates, float* __restrict__ out,
    float* __restrict__ h0seq, float* __restrict__ h1seq,
    int* __restrict__ act_idx, int* __restrict__ jmap, int* __restrict__ S_ptr)
{
    const int b = blockIdx.x, tid = threadIdx.x;
    if (b == 0) {
        __shared__ int sc[NB];
        int d = dates[tid];
        int active = (tid == 0) ? 1 : (d != dates[tid - 1] ? 1 : 0);
        sc[tid] = active;
        for (int off = 1; off < NB; off <<= 1) {
            __syncthreads();
            int v = sc[tid] + ((tid >= off) ? sc[tid - off] : 0);
            __syncthreads();
            sc[tid] = v;
        }
        __syncthreads();
        int incl = sc[tid];               // inclusive actives in [0..tid]
        jmap[tid] = incl - 1;
        if (active) act_idx[incl - 1] = tid;
        if (tid == NB - 1) *S_ptr = incl * TT;
        out[tid] = (float)d;              // output 0: dates passthrough
        for (int i = tid; i < HD; i += 256) { h0seq[i] = 0.f; h1seq[i] = 0.f; }
    } else {
        const uint4 sv = make_uint4(SENT_U, SENT_U, SENT_U, SENT_U);
        const size_t HALF = (size_t)(SEQROWS - 1) * HD / 4;   // uint4 per buffer
        size_t base = (size_t)(b - 1) * 2048 + tid;
#pragma unroll
        for (int k = 0; k < 8; k++) {
            size_t i = base + (size_t)k * 256;                // uint4 index
            uint4* dst = (i < HALF)
                ? reinterpret_cast<uint4*>(h0seq + HD) + i
                : reinterpret_cast<uint4*>(h1seq + HD) + (i - HALF);
            *dst = sv;
        }
    }
}

// ---------------------------------------------------------------------------
// chain: 64 persistent WGs; WG g owns rows hi=g*8+hl of BOTH layers.
// Per iteration s: poll h0(s) -> layer0 -> publish h0(s+1) -> poll h1(s-1)
// -> layer1 (input = h0(s) from LDS) -> publish h1(s). Each chain's
// publish->next-poll window is covered by the OTHER layer's matvec, hiding
// the LLC round trip that limited R5's split-role version to 1.93us/step.
// Communication primitives identical to R5 (fp32 agent-scope atomics).
// All poll loops realtime-clock-bounded: a wedge ends in ~60ms, never hangs.
// Thread (hl=tid>>6, c=tid&63): row hi=g*8+hl, columns {c+64j} j=0..7.
// ---------------------------------------------------------------------------
__global__ __launch_bounds__(512, 2) void chain_kernel(
    const float* __restrict__ x,
    const float* __restrict__ Wih0, const float* __restrict__ Whh0,
    const float* __restrict__ bih0, const float* __restrict__ bhh0,
    const float* __restrict__ Wih1, const float* __restrict__ Whh1,
    const float* __restrict__ bih1, const float* __restrict__ bhh1,
    float* h0seq, float* h1seq,
    const int* __restrict__ act_idx, const int* __restrict__ S_ptr)
{
    const int g   = blockIdx.x;               // 0..63
    const int tid = threadIdx.x;
    const int hl  = tid >> 6;                 // 0..7: local row (one wave per row)
    const int c   = tid & 63;                 // 0..63: column lane
    const int hi  = g * RPW + hl;             // owned row (both layers)

    __shared__ float Abuf[2][HD];             // h0(s) staging, double-buffered
    __shared__ float Bbuf[2][HD];             // h1(s-1) staging

    // ---- 96 register-resident weights/thread (both layers), pinned ----
    float w0ir[RPW], w0iz[RPW], w0in[RPW], w0hr[RPW], w0hz[RPW], w0hn[RPW];
    float w1ir[RPW], w1iz[RPW], w1in[RPW], w1hr[RPW], w1hz[RPW], w1hn[RPW];
    {
        const size_t GS = (size_t)HD * HD;
        const float* rI0 = Wih0 + (size_t)hi * HD + c;
        const float* rH0 = Whh0 + (size_t)hi * HD + c;
        const float* rI1 = Wih1 + (size_t)hi * HD + c;
        const float* rH1 = Whh1 + (size_t)hi * HD + c;
#pragma unroll
        for (int j = 0; j < RPW; j++) {
            w0ir[j] = rI0[64 * j];            pinv(w0ir[j]);
            w0iz[j] = rI0[GS + 64 * j];       pinv(w0iz[j]);
            w0in[j] = rI0[2 * GS + 64 * j];   pinv(w0in[j]);
            w0hr[j] = rH0[64 * j];            pinv(w0hr[j]);
            w0hz[j] = rH0[GS + 64 * j];       pinv(w0hz[j]);
            w0hn[j] = rH0[2 * GS + 64 * j];   pinv(w0hn[j]);
            w1ir[j] = rI1[64 * j];            pinv(w1ir[j]);
            w1iz[j] = rI1[GS + 64 * j];       pinv(w1iz[j]);
            w1in[j] = rI1[2 * GS + 64 * j];   pinv(w1in[j]);
            w1hr[j] = rH1[64 * j];            pinv(w1hr[j]);
            w1hz[j] = rH1[GS + 64 * j];       pinv(w1hz[j]);
            w1hn[j] = rH1[2 * GS + 64 * j];   pinv(w1hn[j]);
        }
    }
    const float b0r  = bih0[hi] + bhh0[hi];
    const float b0z  = bih0[HD + hi] + bhh0[HD + hi];
    const float b0in = bih0[2 * HD + hi];
    const float b0hn = bhh0[2 * HD + hi];
    const float b1r  = bih1[hi] + bhh1[hi];
    const float b1z  = bih1[HD + hi] + bhh1[HD + hi];
    const float b1in = bih1[2 * HD + hi];
    const float b1hn = bhh1[2 * HD + hi];

    const int S = *S_ptr;
    const long long tdead = rtclock() + DEADLINE_TICKS;
    float h0own = 0.f, h1own = 0.f;           // c==0 lanes carry own states

    for (int s = 0; s < S; s++) {
        const int p = s & 1;

        // ---- early probe of h0(s): issue before the overlapped x-compute ----
        const float* hp = h0seq + (size_t)s * HD + tid;
        float hv = coh_load(hp);

        // ---- layer0 x-partials (independent; hides probe RTT) ----
        int n = act_idx[s >> 5];
        const float* xp = x + ((size_t)n * TT + (s & 31)) * HD + c;
        float xr[RPW];
#pragma unroll
        for (int j = 0; j < RPW; j++) xr[j] = xp[64 * j];
        float pr0 = 0.f, pz0 = 0.f, pn0 = 0.f;
#pragma unroll
        for (int j = 0; j < RPW; j++) {
            pr0 = fmaf(w0ir[j], xr[j], pr0);
            pz0 = fmaf(w0iz[j], xr[j], pz0);
            pn0 = fmaf(w0in[j], xr[j], pn0);
        }

        // ---- finish h0(s) poll (deadline-bounded) ----
        while (__float_as_uint(hv) == SENT_U) {
            if (rtclock() > tdead) break;
            hv = coh_load(hp);
        }
        Abuf[p][tid] = hv;
        __syncthreads();                      // B1: Abuf ready

        // ---- early probe of h1(s-1): RTT hides under layer0 matvec ----
        const float* qp = h1seq + (size_t)(s - 1) * HD + tid;
        float qv = 0.f;
        if (s >= 1) qv = coh_load(qp);

        // ---- layer0 h-matvec + gates -> publish h0(s+1) ASAP ----
        float ph0 = 0.f;
#pragma unroll
        for (int j = 0; j < RPW; j++) {
            float a = Abuf[p][c + 64 * j];
            pr0 = fmaf(w0hr[j], a, pr0);
            pz0 = fmaf(w0hz[j], a, pz0);
            ph0 = fmaf(w0hn[j], a, ph0);
        }
#pragma unroll
        for (int m = 1; m < 64; m <<= 1) {
            pr0 += __shfl_xor(pr0, m, 64);
            pz0 += __shfl_xor(pz0, m, 64);
            pn0 += __shfl_xor(pn0, m, 64);
            ph0 += __shfl_xor(ph0, m, 64);
        }
        if (c == 0) {
            float r  = fast_sigmoid(pr0 + b0r);
            float z  = fast_sigmoid(pz0 + b0z);
            float nn = fast_tanh(pn0 + b0in + r * (ph0 + b0hn));
            h0own = (1.f - z) * nn + z * h0own;
            coh_store(h0seq + (size_t)(s + 1) * HD + hi, h0own);
        }

        // ---- layer1: h1(s) = GRU1(h0(s), h1(s-1)); lags one step ----
        if (s >= 1) {
            while (__float_as_uint(qv) == SENT_U) {
                if (rtclock() > tdead) break;
                qv = coh_load(qp);
            }
            Bbuf[p][tid] = qv;
            __syncthreads();                  // B2: Bbuf ready
            float pr1 = 0.f, pz1 = 0.f, pn1 = 0.f, ph1 = 0.f;
#pragma unroll
            for (int j = 0; j < RPW; j++) {
                float a = Abuf[p][c + 64 * j];        // input = h0(s)
                pr1 = fmaf(w1ir[j], a, pr1);
                pz1 = fmaf(w1iz[j], a, pz1);
                pn1 = fmaf(w1in[j], a, pn1);
            }
#pragma unroll
            for (int j = 0; j < RPW; j++) {
                float bb = Bbuf[p][c + 64 * j];       // h = h1(s-1)
                pr1 = fmaf(w1hr[j], bb, pr1);
                pz1 = fmaf(w1hz[j], bb, pz1);
                ph1 = fmaf(w1hn[j], bb, ph1);
            }
#pragma unroll
            for (int m = 1; m < 64; m <<= 1) {
                pr1 += __shfl_xor(pr1, m, 64);
                pz1 += __shfl_xor(pz1, m, 64);
                pn1 += __shfl_xor(pn1, m, 64);
                ph1 += __shfl_xor(ph1, m, 64);
            }
            if (c == 0) {
                float r  = fast_sigmoid(pr1 + b1r);
                float z  = fast_sigmoid(pz1 + b1z);
                float nn = fast_tanh(pn1 + b1in + r * (ph1 + b1hn));
                h1own = (1.f - z) * nn + z * h1own;
                coh_store(h1seq + (size_t)s * HD + hi, h1own);
            }
        }
    }

    // ---- epilogue: h1(S) = GRU1(h0(S), h1(S-1)) ----
    {
        const int p = S & 1;
        const float* hp = h0seq + (size_t)S * HD + tid;
        const float* qp = h1seq + (size_t)(S - 1) * HD + tid;
        float hv = coh_load(hp);
        float qv = coh_load(qp);
        while (__float_as_uint(hv) == SENT_U) {
            if (rtclock() > tdead) break;
            hv = coh_load(hp);
        }
        while (__float_as_uint(qv) == SENT_U) {
            if (rtclock() > tdead) break;
            qv = coh_load(qp);
        }
        Abuf[p][tid] = hv;
        Bbuf[p][tid] = qv;
        __syncthreads();
        float pr1 = 0.f, pz1 = 0.f, pn1 = 0.f, ph1 = 0.f;
#pragma unroll
        for (int j = 0; j < RPW; j++) {
            float a  = Abuf[p][c + 64 * j];
            float bb = Bbuf[p][c + 64 * j];
            pr1 = fmaf(w1ir[j], a, pr1);
            pz1 = fmaf(w1iz[j], a, pz1);
            pn1 = fmaf(w1in[j], a, pn1);
            pr1 = fmaf(w1hr[j], bb, pr1);
            pz1 = fmaf(w1hz[j], bb, pz1);
            ph1 = fmaf(w1hn[j], bb, ph1);
        }
#pragma unroll
        for (int m = 1; m < 64; m <<= 1) {
            pr1 += __shfl_xor(pr1, m, 64);
            pz1 += __shfl_xor(pz1, m, 64);
            pn1 += __shfl_xor(pn1, m, 64);
            ph1 += __shfl_xor(ph1, m, 64);
        }
        if (c == 0) {
            float r  = fast_sigmoid(pr1 + b1r);
            float z  = fast_sigmoid(pz1 + b1z);
            float nn = fast_tanh(pn1 + b1in + r * (ph1 + b1hn));
            h1own = (1.f - z) * nn + z * h1own;
            coh_store(h1seq + (size_t)S * HD + hi, h1own);
        }
    }
}

// ---------------------------------------------------------------------------
// finalize: states[n] = h1 after (jmap[n]+1)*32 steps.  (verbatim R5)
// ---------------------------------------------------------------------------
__global__ __launch_bounds__(256) void finalize_kernel(
    const float* __restrict__ h1seq, const int* __restrict__ jmap,
    float* __restrict__ out)
{
    const int n = blockIdx.x;
    const int j = jmap[n];
    const float* src = h1seq + ((size_t)j * TT + TT) * HD;   // row (j+1)*32
    float* dst = out + NB + (size_t)n * HD;
    for (int i = threadIdx.x; i < HD; i += 256)
        dst[i] = __hip_atomic_load(src + i, __ATOMIC_RELAXED,
                                   __HIP_MEMORY_SCOPE_AGENT);
}

extern "C" void kernel_launch(void* const* d_in, const int* in_sizes, int n_in,
                              void* d_out, int out_size, void* d_ws, size_t ws_size,
                              hipStream_t stream)
{
    const int*   dates = (const int*)d_in[0];
    const float* x     = (const float*)d_in[1];
    const float* Wih0  = (const float*)d_in[2];
    const float* Whh0  = (const float*)d_in[3];
    const float* bih0  = (const float*)d_in[4];
    const float* bhh0  = (const float*)d_in[5];
    const float* Wih1  = (const float*)d_in[6];
    const float* Whh1  = (const float*)d_in[7];
    const float* bih1  = (const float*)d_in[8];
    const float* bhh1  = (const float*)d_in[9];
    float* out = (float*)d_out;

    // workspace layout (~33.6 MB, same as R5)
    float* h0seq = (float*)d_ws;                        // 8193*512
    float* h1seq = h0seq + (size_t)SEQROWS * HD;        // 8193*512
    int*   act_i = (int*)(h1seq + (size_t)SEQROWS * HD);
    int*   jmap  = act_i + NB;                          // 256
    int*   S_ptr = jmap + NB;                           // 1

    hipLaunchKernelGGL(init_kernel, dim3(1025), dim3(256), 0, stream,
                       dates, out, h0seq, h1seq, act_i, jmap, S_ptr);
    hipLaunchKernelGGL(chain_kernel, dim3(GC), dim3(512), 0, stream,
                       x, Wih0, Whh0, bih0, bhh0, Wih1, Whh1, bih1, bhh1,
                       h0seq, h1seq, act_i, S_ptr);
    hipLaunchKernelGGL(finalize_kernel, dim3(NB), dim3(256), 0, stream,
                       h1seq, jmap, out);
}

// Round 10
// 10780.656 us; speedup vs baseline: 1.0930x; 1.0930x over previous
//
#include <hip/hip_runtime.h>

// Problem dims (fixed by reference): N=256, T=32, F=H=512, L=2
#define HD 512
#define TT 32
#define NB 256
#define SEQROWS 8193          // 1 zero row + up to 8192 chain steps
#define GR 16                 // WGs per role (A=layer0, B=layer1); 32 chain WGs total
#define ROWS 32               // h rows owned per WG (GR*ROWS = HD)
#define COLS 16               // column lanes per row (ROWS*COLS = 512 threads)
#define ELEMS 32              // elements per thread per weight array (HD/COLS)
#define SENT_U 0x7FC0ABCDu    // quiet-NaN sentinel: unreachable by GRU math
#define XCC_IMM 6164          // s_getreg imm: id=20 (HW_REG_XCC_ID) | off 0 | (4-1)<<11
#define REND_TICKS 20000ll    // 200 us rendezvous timeout @ 100 MHz
#define DEAD_TICKS 4000000ll  // 40 ms hard deadline: bounded, never hangs
#define BUD_EARLY 1024        // phase-1 poll budget, steps 0..7 (pipeline fill)
#define BUD_STEADY 32         // phase-1 poll budget, steady state
#define EARLY_STEPS 8
#define ESC_DEMOTE 3          // per-lane: demote to LLC after 3 escalations

__device__ __forceinline__ float fast_sigmoid(float x) { return 1.f / (1.f + __expf(-x)); }
__device__ __forceinline__ float fast_tanh(float x)    { return 1.f - 2.f / (__expf(2.f * x) + 1.f); }
__device__ __forceinline__ void pinv(float& v) { asm volatile("" : "+v"(v)); }
__device__ __forceinline__ long long rtclock() {
    return (long long)__builtin_amdgcn_s_memrealtime();
}

// ---------------------------------------------------------------------------
// Channel: correctness NEVER depends on placement.
// publish = agent-scope atomic store (LLC shadow, R5-proven) + workgroup-scope
// atomic_exchange (executes in producer's L2; atomics never live in L1).
// poll    = phase-1 workgroup-scope uint fetch_add(+0) (bit-exact, executes in
// consumer's L2 -> same-XCD detect ~250cyc) with bounded budget; phase-2 =
// agent-scope load of the LLC shadow (always succeeds). Per-lane demotion
// turns a wrong placement into ~R5 speed instead of failure (R9's mistake).
// ---------------------------------------------------------------------------
__device__ __forceinline__ void chan_pub(float* p, float val, bool fast) {
    unsigned* up = (unsigned*)p;
    unsigned bits = __float_as_uint(val);
    __hip_atomic_store(up, bits, __ATOMIC_RELAXED, __HIP_MEMORY_SCOPE_AGENT);
    if (fast)
        (void)__hip_atomic_exchange(up, bits, __ATOMIC_RELAXED,
                                    __HIP_MEMORY_SCOPE_WORKGROUP);
}
__device__ __forceinline__ float chan_poll(float* p, bool fast, bool& demoted,
                                           int& esc, int s, long long tdead) {
    unsigned* up = (unsigned*)p;
    unsigned v;
    if (fast && !demoted) {
        const int bud = (s < EARLY_STEPS) ? BUD_EARLY : BUD_STEADY;
        v = __hip_atomic_fetch_add(up, 0u, __ATOMIC_RELAXED,
                                   __HIP_MEMORY_SCOPE_WORKGROUP);
        for (int it = 0; v == SENT_U && it < bud; ++it)
            v = __hip_atomic_fetch_add(up, 0u, __ATOMIC_RELAXED,
                                       __HIP_MEMORY_SCOPE_WORKGROUP);
        if (v != SENT_U) return __uint_as_float(v);
        if (s >= EARLY_STEPS && ++esc >= ESC_DEMOTE) demoted = true;
    }
    v = __hip_atomic_load(up, __ATOMIC_RELAXED, __HIP_MEMORY_SCOPE_AGENT);
    int it = 0;
    while (v == SENT_U) {
        if (((++it) & 255) == 0 && rtclock() > tdead) break;   // fail loudly
        v = __hip_atomic_load(up, __ATOMIC_RELAXED, __HIP_MEMORY_SCOPE_AGENT);
    }
    return __uint_as_float(v);
}

// ---------------------------------------------------------------------------
// init: block 0 -> dates scan, active list, jmap, S, zero h row 0, control
//       words, out dates; blocks 1..1024 -> sentinel-fill rows 1..8192 of
//       both fp32 h buffers. (structure proven R5-R9)
// ---------------------------------------------------------------------------
__global__ __launch_bounds__(256) void init_kernel(
    const int* __restrict__ dates, float* __restrict__ out,
    float* __restrict__ h0seq, float* __restrict__ h1seq,
    int* __restrict__ act_idx, int* __restrict__ jmap, int* __restrict__ S_ptr,
    int* __restrict__ xcd_cnt, int* __restrict__ winner, int* __restrict__ fb_cnt)
{
    const int b = blockIdx.x, tid = threadIdx.x;
    if (b == 0) {
        __shared__ int sc[NB];
        int d = dates[tid];
        int active = (tid == 0) ? 1 : (d != dates[tid - 1] ? 1 : 0);
        sc[tid] = active;
        for (int off = 1; off < NB; off <<= 1) {
            __syncthreads();
            int v = sc[tid] + ((tid >= off) ? sc[tid - off] : 0);
            __syncthreads();
            sc[tid] = v;
        }
        __syncthreads();
        int incl = sc[tid];               // inclusive actives in [0..tid]
        jmap[tid] = incl - 1;
        if (active) act_idx[incl - 1] = tid;
        if (tid == NB - 1) *S_ptr = incl * TT;
        if (tid == 0) { *winner = -1; *fb_cnt = 0; }
        if (tid < 8) xcd_cnt[tid] = 0;
        out[tid] = (float)d;              // output 0: dates passthrough
        for (int i = tid; i < HD; i += 256) { h0seq[i] = 0.f; h1seq[i] = 0.f; }
    } else {
        const uint4 sv = make_uint4(SENT_U, SENT_U, SENT_U, SENT_U);
        const size_t HALF = (size_t)(SEQROWS - 1) * HD / 4;   // uint4 per buffer
        size_t base = (size_t)(b - 1) * 2048 + tid;
#pragma unroll
        for (int k = 0; k < 8; k++) {
            size_t i = base + (size_t)k * 256;                // uint4 index
            uint4* dst = (i < HALF)
                ? reinterpret_cast<uint4*>(h0seq + HD) + i
                : reinterpret_cast<uint4*>(h1seq + HD) + (i - HALF);
            *dst = sv;
        }
    }
}

// ---------------------------------------------------------------------------
// chain: 256 candidate WGs. First XCD to accumulate 32 arrivals wins; its
// 32 WGs claim slots (0..15 -> layer0 "A", 16..31 -> layer1 "B"). Claim only
// selects fast-mode; correctness is placement-independent (see chan_*).
// Timeout -> LLC mode via global tickets (R5 primitives exactly).
// Thread (hl=tid>>4, c=tid&15): row hi=gg*32+hl, columns {c+16j} j=0..31.
// 192 pinned fp32 weights/thread; launch_bounds(512) only.
// ---------------------------------------------------------------------------
__global__ __launch_bounds__(512) void chain_kernel(
    const float* __restrict__ x,
    const float* __restrict__ Wih0, const float* __restrict__ Whh0,
    const float* __restrict__ bih0, const float* __restrict__ bhh0,
    const float* __restrict__ Wih1, const float* __restrict__ Whh1,
    const float* __restrict__ bih1, const float* __restrict__ bhh1,
    float* h0seq, float* h1seq,
    const int* __restrict__ act_idx, const int* __restrict__ S_ptr,
    int* xcd_cnt, int* winner, int* fb_cnt)
{
    __shared__ int s_g, s_mode;
    __shared__ float Abuf[HD], Bbuf[HD];
    __shared__ float gbuf[ROWS];
    const int tid = threadIdx.x;

    if (tid == 0) {
        int xcc = __builtin_amdgcn_s_getreg(XCC_IMM) & 7;
        int t = __hip_atomic_fetch_add(xcd_cnt + xcc, 1, __ATOMIC_RELAXED,
                                       __HIP_MEMORY_SCOPE_AGENT);
        if (t == 2 * GR - 1) {
            int e = -1;
            __hip_atomic_compare_exchange_strong(winner, &e, xcc,
                __ATOMIC_RELAXED, __ATOMIC_RELAXED, __HIP_MEMORY_SCOPE_AGENT);
        }
        long long tr = rtclock() + REND_TICKS;
        int g = -1, mode = 0;
        for (int it = 0; it < 50000000; ++it) {
            int w = __hip_atomic_load(winner, __ATOMIC_RELAXED,
                                      __HIP_MEMORY_SCOPE_AGENT);
            if (w >= 0) { if (w == xcc && t < 2 * GR) g = t; break; }
            if (w == -2) {
                int ft = __hip_atomic_fetch_add(fb_cnt, 1, __ATOMIC_RELAXED,
                                                __HIP_MEMORY_SCOPE_AGENT);
                if (ft < 2 * GR) { g = ft; mode = 1; }
                break;
            }
            if (rtclock() > tr) {
                int e = -1;
                __hip_atomic_compare_exchange_strong(winner, &e, -2,
                    __ATOMIC_RELAXED, __ATOMIC_RELAXED, __HIP_MEMORY_SCOPE_AGENT);
            }
        }
        s_g = g; s_mode = mode;
    }
    __syncthreads();
    const int g = s_g;
    const bool fast = (s_mode == 0);
    if (g < 0) return;                       // unclaimed: retire

    const bool roleB = (g >= GR);
    const int gg = roleB ? g - GR : g;       // 0..15 within role
    const int hl = tid >> 4;                 // 0..31: local row
    const int c  = tid & 15;                 // 0..15: column lane
    const int hi = gg * ROWS + hl;           // owned h output index

    const float* Wi = roleB ? Wih1 : Wih0;
    const float* Wh = roleB ? Whh1 : Whh0;
    const float* bi = roleB ? bih1 : bih0;
    const float* bh = roleB ? bhh1 : bhh0;

    // ---- 192 register-resident weights/thread (columns c + 16j), pinned ----
    float wi_r[ELEMS], wi_z[ELEMS], wi_n[ELEMS];
    float wh_r[ELEMS], wh_z[ELEMS], wh_n[ELEMS];
    {
        const size_t GS = (size_t)HD * HD;
        const float* rI = Wi + (size_t)hi * HD + c;
        const float* rH = Wh + (size_t)hi * HD + c;
#pragma unroll
        for (int j = 0; j < ELEMS; j++) {
            wi_r[j] = rI[COLS * j];            pinv(wi_r[j]);
            wi_z[j] = rI[GS + COLS * j];       pinv(wi_z[j]);
            wi_n[j] = rI[2 * GS + COLS * j];   pinv(wi_n[j]);
            wh_r[j] = rH[COLS * j];            pinv(wh_r[j]);
            wh_z[j] = rH[GS + COLS * j];       pinv(wh_z[j]);
            wh_n[j] = rH[2 * GS + COLS * j];   pinv(wh_n[j]);
        }
    }
    const float br   = bi[hi] + bh[hi];
    const float bz   = bi[HD + hi] + bh[HD + hi];
    const float bin_ = bi[2 * HD + hi];
    const float bhn_ = bh[2 * HD + hi];

    const int S = *S_ptr;
    const long long tdead = rtclock() + DEAD_TICKS;
    float hown = 0.f;                        // c==0 lanes carry own state
    bool demoted = !fast;                    // LLC mode: phase-1 skipped
    int esc = 0;

    for (int s = 0; s < S; s++) {
        float pr = 0.f, pz = 0.f, pn = 0.f;

        if (!roleB) {
            // ---- role A: x slice + input-partials BEFORE the poll ----
            int n = act_idx[s >> 5];
            const float* xp = x + ((size_t)n * TT + (s & 31)) * HD + c;
#pragma unroll
            for (int j = 0; j < ELEMS; j++) {
                float xv = xp[COLS * j];
                pr = fmaf(wi_r[j], xv, pr);
                pz = fmaf(wi_z[j], xv, pz);
                pn = fmaf(wi_n[j], xv, pn);
            }
            // ---- poll own prev row h0(s) ----
            Abuf[tid] = chan_poll(h0seq + (size_t)s * HD + tid, fast,
                                  demoted, esc, s, tdead);
        } else {
            // ---- role B: input h0(s+1) (ready early) then own h1(s) ----
            Abuf[tid] = chan_poll(h0seq + (size_t)(s + 1) * HD + tid, fast,
                                  demoted, esc, s, tdead);
            Bbuf[tid] = chan_poll(h1seq + (size_t)s * HD + tid, fast,
                                  demoted, esc, s, tdead);
        }
        __syncthreads();                      // staging ready

        if (roleB) {
#pragma unroll
            for (int j = 0; j < ELEMS; j++) {
                float a = Abuf[c + COLS * j];
                pr = fmaf(wi_r[j], a, pr);
                pz = fmaf(wi_z[j], a, pz);
                pn = fmaf(wi_n[j], a, pn);
            }
        }
        float ph = 0.f;
        const float* hrow = roleB ? Bbuf : Abuf;
#pragma unroll
        for (int j = 0; j < ELEMS; j++) {
            float a = hrow[c + COLS * j];
            pr = fmaf(wh_r[j], a, pr);
            pz = fmaf(wh_z[j], a, pz);
            ph = fmaf(wh_n[j], a, ph);
        }
        // ---- reduce across the 16 column lanes (in-wave, groups of 16) ----
#pragma unroll
        for (int m = 1; m < COLS; m <<= 1) {
            pr += __shfl_xor(pr, m, 64);
            pz += __shfl_xor(pz, m, 64);
            pn += __shfl_xor(pn, m, 64);
            ph += __shfl_xor(ph, m, 64);
        }
        if (c == 0) {
            float r  = fast_sigmoid(pr + br);
            float z  = fast_sigmoid(pz + bz);
            float nn = fast_tanh(pn + bin_ + r * (ph + bhn_));
            hown = (1.f - z) * nn + z * hown;
            gbuf[hl] = hown;                  // gather for coalesced publish
        }
        __syncthreads();
        // ---- publish: lanes 0..31 -> one contiguous 128B span, dual-write ----
        if (tid < ROWS) {
            float* dst = (roleB ? h1seq : h0seq)
                         + (size_t)(s + 1) * HD + gg * ROWS + tid;
            chan_pub(dst, gbuf[tid], fast);
        }
    }
}

// ---------------------------------------------------------------------------
// finalize: states[n] = h1 after (jmap[n]+1)*32 steps. Values are always in
// the LLC shadow (agent-scope store on every publish) -> agent loads see them.
// ---------------------------------------------------------------------------
__global__ __launch_bounds__(256) void finalize_kernel(
    const float* __restrict__ h1seq, const int* __restrict__ jmap,
    float* __restrict__ out)
{
    const int n = blockIdx.x;
    const int j = jmap[n];
    const float* src = h1seq + ((size_t)j * TT + TT) * HD;   // row (j+1)*32
    float* dst = out + NB + (size_t)n * HD;
    for (int i = threadIdx.x; i < HD; i += 256)
        dst[i] = __hip_atomic_load(src + i, __ATOMIC_RELAXED,
                                   __HIP_MEMORY_SCOPE_AGENT);
}

extern "C" void kernel_launch(void* const* d_in, const int* in_sizes, int n_in,
                              void* d_out, int out_size, void* d_ws, size_t ws_size,
                              hipStream_t stream)
{
    const int*   dates = (const int*)d_in[0];
    const float* x     = (const float*)d_in[1];
    const float* Wih0  = (const float*)d_in[2];
    const float* Whh0  = (const float*)d_in[3];
    const float* bih0  = (const float*)d_in[4];
    const float* bhh0  = (const float*)d_in[5];
    const float* Wih1  = (const float*)d_in[6];
    const float* Whh1  = (const float*)d_in[7];
    const float* bih1  = (const float*)d_in[8];
    const float* bhh1  = (const float*)d_in[9];
    float* out = (float*)d_out;

    // workspace layout (~33.6 MB)
    float* h0seq  = (float*)d_ws;                       // 8193*512
    float* h1seq  = h0seq + (size_t)SEQROWS * HD;       // 8193*512
    int*   act_i  = (int*)(h1seq + (size_t)SEQROWS * HD);
    int*   jmap   = act_i + NB;                         // 256
    int*   S_ptr  = jmap + NB;                          // 1
    int*   xcd_c  = S_ptr + 1;                          // 8
    int*   winner = xcd_c + 8;                          // 1
    int*   fb_cnt = winner + 1;                         // 1

    hipLaunchKernelGGL(init_kernel, dim3(1025), dim3(256), 0, stream,
                       dates, out, h0seq, h1seq, act_i, jmap, S_ptr,
                       xcd_c, winner, fb_cnt);
    hipLaunchKernelGGL(chain_kernel, dim3(256), dim3(512), 0, stream,
                       x, Wih0, Whh0, bih0, bhh0, Wih1, Whh1, bih1, bhh1,
                       h0seq, h1seq, act_i, S_ptr, xcd_c, winner, fb_cnt);
    hipLaunchKernelGGL(finalize_kernel, dim3(NB), dim3(256), 0, stream,
                       h1seq, jmap, out);
}

// Round 11
// 7961.224 us; speedup vs baseline: 1.4801x; 1.3541x over previous
//
#include <hip/hip_runtime.h>
#include <hip/hip_bf16.h>

// Problem dims (fixed by reference): N=256, T=32, F=H=512, L=2
#define HD 512
#define TT 32
#define NB 256
#define SEQROWS 8193          // 1 zero row + up to 8192 chain steps
#define GA 32                 // workgroups per role (A=layer0, B=layer1)
#define SENT_U 0x7FC0ABCDu    // quiet-NaN sentinel: unreachable by GRU math
#define TAU 120ull            // schedule period, 10ns ticks (1.2us @100MHz)
                              // R5 ran TAU=90 (always expired -> natural 1.93us);
                              // 120 is chosen to BIND: produce+commit ~0.9us fits.
#define T0_MARGIN 500ull      // 5us margin between rendezvous and step 0

__device__ __forceinline__ float fast_sigmoid(float x) {
    return 1.0f / (1.0f + __expf(-x));
}
__device__ __forceinline__ float fast_tanh(float x) {
    return 1.0f - 2.0f / (__expf(2.0f * x) + 1.0f);
}
__device__ __forceinline__ void pinv(float& v) { asm volatile("" : "+v"(v)); }

__device__ __forceinline__ float llc_load(const float* p) {
    return __hip_atomic_load(p, __ATOMIC_RELAXED, __HIP_MEMORY_SCOPE_AGENT);
}
__device__ __forceinline__ void llc_store(float* p, float v) {
    __hip_atomic_store(p, v, __ATOMIC_RELAXED, __HIP_MEMORY_SCOPE_AGENT);
}

// ---------------------------------------------------------------------------
// init: block 0 -> dates scan, active list, jmap, S, zero h row 0, rendezvous
//       slots, out dates; blocks 1..1024 -> sentinel-fill rows 1..8192.
// (verbatim R5 — proven)
// ---------------------------------------------------------------------------
__global__ __launch_bounds__(256) void init_kernel(
    const int* __restrict__ dates, float* __restrict__ out,
    float* __restrict__ h0seq, float* __restrict__ h1seq,
    int* __restrict__ act_idx, int* __restrict__ jmap, int* __restrict__ S_ptr,
    int* __restrict__ arrive, unsigned long long* __restrict__ t0_slot)
{
    const int b = blockIdx.x, tid = threadIdx.x;
    if (b == 0) {
        __shared__ int sc[NB];
        int d = dates[tid];
        int active = (tid == 0) ? 1 : (d != dates[tid - 1] ? 1 : 0);
        sc[tid] = active;
        for (int off = 1; off < NB; off <<= 1) {
            __syncthreads();
            int v = sc[tid] + ((tid >= off) ? sc[tid - off] : 0);
            __syncthreads();
            sc[tid] = v;
        }
        __syncthreads();
        int incl = sc[tid];               // inclusive actives in [0..tid]
        jmap[tid] = incl - 1;
        if (active) act_idx[incl - 1] = tid;
        if (tid == NB - 1) *S_ptr = incl * TT;
        if (tid == 0) { *arrive = 0; *t0_slot = 0ull; }
        out[tid] = (float)d;              // output 0: dates passthrough
        for (int i = tid; i < HD; i += 256) { h0seq[i] = 0.f; h1seq[i] = 0.f; }
    } else {
        const uint4 sv = make_uint4(SENT_U, SENT_U, SENT_U, SENT_U);
        const size_t HALF = (size_t)(SEQROWS - 1) * HD / 4;   // uint4 per buffer
        size_t base = (size_t)(b - 1) * 2048 + tid;
#pragma unroll
        for (int k = 0; k < 8; k++) {
            size_t i = base + (size_t)k * 256;                // uint4 index
            uint4* dst = (i < HALF)
                ? reinterpret_cast<uint4*>(h0seq + HD) + i
                : reinterpret_cast<uint4*>(h1seq + HD) + (i - HALF);
            *dst = sv;
        }
    }
}

// ---------------------------------------------------------------------------
// chain: 64 persistent WGs, clock-scheduled pipeline (s_memrealtime-gated,
// sentinel fallback). WGs 0..31 = layer0 (input x), 32..63 = layer1.
// Thread (hl=tid>>5, c=tid&31) owns row hi=g*16+hl, cols {c+32j} j=0..15.
// Publication: 16 leader values gathered in LDS, stored by lanes 0..15 of
// wave 0 as ONE 64B coalesced LLC transaction.
// Schedule: T0 published by last rendezvous arriver (same VALUE for all WGs
// => zero schedule skew); role A step s gated at T0+s*TAU, role B at +1 slot.
// With TAU=120 the gate BINDS: consumers poll ~0.3us after data is visible,
// eliminating the contention/quantization that set R5's natural 1.93us/step.
// ---------------------------------------------------------------------------
__global__ __launch_bounds__(512, 2) void chain_kernel(
    const float* __restrict__ x,
    const float* __restrict__ Wih0, const float* __restrict__ Whh0,
    const float* __restrict__ bih0, const float* __restrict__ bhh0,
    const float* __restrict__ Wih1, const float* __restrict__ Whh1,
    const float* __restrict__ bih1, const float* __restrict__ bhh1,
    float* h0seq, float* h1seq,
    const int* __restrict__ act_idx, const int* __restrict__ S_ptr,
    int* arrive, unsigned long long* t0_slot)
{
    const int wg   = blockIdx.x;
    const bool roleB = (wg >= GA);
    const int g    = roleB ? wg - GA : wg;     // 0..31
    const int tid  = threadIdx.x;
    const int hl   = tid >> 5;                 // 0..15: local h row
    const int c    = tid & 31;                 // 0..31: column lane
    const int hi   = g * 16 + hl;              // owned h output index

    __shared__ float hbuf[HD];                 // own-role h(s-1) row
    __shared__ float xbuf[HD];                 // role B: h0(s) row
    __shared__ float gbuf[16];                 // publication gather

    const float* Wi = roleB ? Wih1 : Wih0;
    const float* Wh = roleB ? Whh1 : Whh0;
    const float* bi = roleB ? bih1 : bih0;
    const float* bh = roleB ? bhh1 : bhh0;

    // ---- 96 weights/thread (pinned; allocator may AGPR-home them: fine) ----
    float wir[16], wiz[16], win[16], whr[16], whz[16], whn[16];
    {
        const size_t GS = (size_t)HD * HD;
        const float* rI = Wi + (size_t)hi * HD + c;
        const float* rH = Wh + (size_t)hi * HD + c;
#pragma unroll
        for (int j = 0; j < 16; j++) {
            wir[j] = rI[32 * j];            pinv(wir[j]);
            wiz[j] = rI[GS + 32 * j];       pinv(wiz[j]);
            win[j] = rI[2 * GS + 32 * j];   pinv(win[j]);
            whr[j] = rH[32 * j];            pinv(whr[j]);
            whz[j] = rH[GS + 32 * j];       pinv(whz[j]);
            whn[j] = rH[2 * GS + 32 * j];   pinv(whn[j]);
        }
    }
    const float br   = bi[hi] + bh[hi];
    const float bz   = bi[HD + hi] + bh[HD + hi];
    const float bin_ = bi[2 * HD + hi];
    const float bhn_ = bh[2 * HD + hi];
    const int S = *S_ptr;

    // ---- rendezvous: weights loaded; last arriver publishes T0 value ----
    if (tid == 0) {
        int t = __hip_atomic_fetch_add(arrive, 1, __ATOMIC_RELAXED,
                                       __HIP_MEMORY_SCOPE_AGENT);
        if (t == 2 * GA - 1) {
            unsigned long long t0 = __builtin_amdgcn_s_memrealtime() + T0_MARGIN;
            __hip_atomic_store(t0_slot, t0, __ATOMIC_RELAXED,
                               __HIP_MEMORY_SCOPE_AGENT);
        }
    }
    // all threads poll the T0 value (same number everywhere -> zero skew)
    unsigned long long T0 = 0;
    {
        int it = 0;
        while ((T0 = __hip_atomic_load(t0_slot, __ATOMIC_RELAXED,
                                       __HIP_MEMORY_SCOPE_AGENT)) == 0ull) {
            __builtin_amdgcn_s_sleep(1);
            if (++it > 50000000) break;
        }
    }

    float* outseq = roleB ? h1seq : h0seq;
    float hown = 0.0f;
    unsigned long long gate = T0 + (roleB ? TAU : 0ull);

    for (int s = 0; s < S; s++, gate += TAU) {
        // ---- role A: x slice + x-partials BEFORE the gate (overlapped) ----
        float pr = 0.f, pz = 0.f, pin_ = 0.f;
        if (!roleB) {
            int n = act_idx[s >> 5];
            const float* xp = x + ((size_t)n * TT + (s & 31)) * HD + c;
            float xr[16];
#pragma unroll
            for (int j = 0; j < 16; j++) xr[j] = xp[32 * j];
#pragma unroll
            for (int j = 0; j < 16; j++) {
                pr   = fmaf(wir[j], xr[j], pr);
                pz   = fmaf(wiz[j], xr[j], pz);
                pin_ = fmaf(win[j], xr[j], pin_);
            }
        }

        // ---- wait for the schedule gate (SALU only, zero memory traffic) ----
        while ((long long)(__builtin_amdgcn_s_memrealtime() - gate) < 0) {}

        // ---- load input rows once; sentinel fallback if producer late ----
        const float* hp = outseq + (size_t)s * HD + tid;
        float hv = llc_load(hp);
        if (!roleB) {
            int it = 0;
            while (__float_as_uint(hv) == SENT_U) {
                __builtin_amdgcn_s_sleep(1);
                hv = llc_load(hp);
                if (++it > 20000000) break;
            }
            hbuf[tid] = hv;
        } else {
            const float* xp2 = h0seq + (size_t)(s + 1) * HD + tid;
            float xv = llc_load(xp2);
            int it = 0;
            while (__float_as_uint(hv) == SENT_U || __float_as_uint(xv) == SENT_U) {
                __builtin_amdgcn_s_sleep(1);
                if (__float_as_uint(hv) == SENT_U) hv = llc_load(hp);
                if (__float_as_uint(xv) == SENT_U) xv = llc_load(xp2);
                if (++it > 20000000) break;
            }
            hbuf[tid] = hv;
            xbuf[tid] = xv;
        }
        __syncthreads();

        // ---- matvec partials ----
        float phn = 0.f;
#pragma unroll
        for (int j = 0; j < 16; j++) {
            float h2 = hbuf[c + 32 * j];
            pr  = fmaf(whr[j], h2, pr);
            pz  = fmaf(whz[j], h2, pz);
            phn = fmaf(whn[j], h2, phn);
        }
        if (roleB) {
#pragma unroll
            for (int j = 0; j < 16; j++) {
                float x2 = xbuf[c + 32 * j];
                pr   = fmaf(wir[j], x2, pr);
                pz   = fmaf(wiz[j], x2, pz);
                pin_ = fmaf(win[j], x2, pin_);
            }
        }
#pragma unroll
        for (int m = 1; m < 32; m <<= 1) {
            pr   += __shfl_xor(pr,   m, 64);
            pz   += __shfl_xor(pz,   m, 64);
            pin_ += __shfl_xor(pin_, m, 64);
            phn  += __shfl_xor(phn,  m, 64);
        }
        if (c == 0) {
            float r  = fast_sigmoid(pr + br);
            float z  = fast_sigmoid(pz + bz);
            float nn = fast_tanh(pin_ + bin_ + r * (phn + bhn_));
            hown = (1.0f - z) * nn + z * hown;
            gbuf[hl] = hown;                   // gather for single-line publish
        }
        __syncthreads();
        // ---- publish: lanes 0..15 of wave 0 -> ONE 64B LLC transaction ----
        if (tid < 16)
            llc_store(outseq + (size_t)(s + 1) * HD + g * 16 + tid, gbuf[tid]);
    }
}

// ---------------------------------------------------------------------------
// finalize: states[n] = h1 after last step of active element jmap[n].
// ---------------------------------------------------------------------------
__global__ __launch_bounds__(256) void finalize_kernel(
    const float* __restrict__ h1seq, const int* __restrict__ jmap,
    float* __restrict__ out)
{
    const int n = blockIdx.x;
    const int j = jmap[n];
    const float* src = h1seq + ((size_t)j * TT + TT) * HD;   // row (j+1)*32
    float* dst = out + NB + (size_t)n * HD;
    for (int i = threadIdx.x; i < HD; i += 256)
        dst[i] = __hip_atomic_load(src + i, __ATOMIC_RELAXED,
                                   __HIP_MEMORY_SCOPE_AGENT);
}

extern "C" void kernel_launch(void* const* d_in, const int* in_sizes, int n_in,
                              void* d_out, int out_size, void* d_ws, size_t ws_size,
                              hipStream_t stream)
{
    const int*   dates = (const int*)d_in[0];
    const float* x     = (const float*)d_in[1];
    const float* Wih0  = (const float*)d_in[2];
    const float* Whh0  = (const float*)d_in[3];
    const float* bih0  = (const float*)d_in[4];
    const float* bhh0  = (const float*)d_in[5];
    const float* Wih1  = (const float*)d_in[6];
    const float* Whh1  = (const float*)d_in[7];
    const float* bih1  = (const float*)d_in[8];
    const float* bhh1  = (const float*)d_in[9];
    float* out = (float*)d_out;

    // workspace layout (~33.6 MB)
    float* h0seq  = (float*)d_ws;                       // 8193*512
    float* h1seq  = h0seq + (size_t)SEQROWS * HD;       // 8193*512
    int*   act_i  = (int*)(h1seq + (size_t)SEQROWS * HD);
    int*   jmap   = act_i + NB;                         // 256
    int*   S_ptr  = jmap + NB;                          // 1
    int*   arrive = S_ptr + 1;                          // 1
    unsigned long long* t0_slot =
        (unsigned long long*)(arrive + 3);              // 8B-aligned

    hipLaunchKernelGGL(init_kernel, dim3(1025), dim3(256), 0, stream,
                       dates, out, h0seq, h1seq, act_i, jmap, S_ptr,
                       arrive, t0_slot);
    hipLaunchKernelGGL(chain_kernel, dim3(2 * GA), dim3(512), 0, stream,
                       x, Wih0, Whh0, bih0, bhh0, Wih1, Whh1, bih1, bhh1,
                       h0seq, h1seq, act_i, S_ptr, arrive, t0_slot);
    hipLaunchKernelGGL(finalize_kernel, dim3(NB), dim3(256), 0, stream,
                       h1seq, jmap, out);
}